// Round 2
// baseline (2247.987 us; speedup 1.0000x reference)
//
#include <hip/hip_runtime.h>
#include <stdint.h>

#define B_ 128
#define T_ 2048
#define I_ 256
#define H_ 256

// ---------- gate helpers (overflow-safe, fp32) ----------

__device__ __forceinline__ void gates_sg(float z, float& s, float& g){
  float az = fabsf(z);
  float a  = __expf(-az);                          // in (0,1]
  float r1 = __builtin_amdgcn_rcpf(1.0f + a);
  s = (z >= 0.0f) ? r1 : a * r1;                   // sigmoid(z)
  float a2 = a * a;
  float gm = (1.0f - a2) * __builtin_amdgcn_rcpf(1.0f + a2);
  g = (z >= 0.0f) ? gm : -gm;                      // tanh(z)
}
__device__ __forceinline__ float tanh_stable(float c){
  float ac = fabsf(c);
  float u  = __expf(-2.0f * ac);                   // underflows to 0, never Inf
  float tm = (1.0f - u) * __builtin_amdgcn_rcpf(1.0f + u);
  return (c >= 0.0f) ? tm : -tm;
}

#define FMA4(hs, wv, ax, ay, az, aw)            \
  ax = fmaf(hs, wv.x, ax); ay = fmaf(hs, wv.y, ay); \
  az = fmaf(hs, wv.z, az); aw = fmaf(hs, wv.w, aw);

// ---------- phase 1: xp[b, j, t] = x[b,t,:] @ w_x[:,j] + b_x[j] + b_h[j]  (fp32, [B,H,Tc]) ----------
// 512 threads = 8 waves; wave w owns k-slice [32w, 32w+32); lane owns cols 4*lane..4*lane+3.

__global__ __launch_bounds__(512, 2) void xproj_k(
    const float* __restrict__ x, const float* __restrict__ w_x,
    const float* __restrict__ b_x, const float* __restrict__ b_h,
    float* __restrict__ xp, int t0c, int Tc)
{
  const int tid  = threadIdx.x;
  const int wv   = tid >> 6;
  const int lane = tid & 63;
  const int ks   = wv * 32;

  float4 w4[32];                                   // 128 VGPRs of weights
  #pragma unroll
  for (int kk = 0; kk < 32; ++kk)
    w4[kk] = *(const float4*)&w_x[(ks + kk) * H_ + 4 * lane];

  float bias = 0.0f;
  if (tid < 256) bias = b_x[tid] + b_h[tid];

  __shared__ float4 xs4[256];                      // 4 rows x 256 floats (4 KB)
  __shared__ float  pb[8][4][256];                 // [wave][row][col] (32 KB)

  const int rows_per_b = Tc >> 2;
  const int nblk = (B_ * Tc) >> 2;
  for (int bid = blockIdx.x; bid < nblk; bid += gridDim.x){
    const int b  = bid / rows_per_b;
    const int t4 = (bid - b * rows_per_b) << 2;    // local t within chunk
    __syncthreads();                               // protect xs4/pb reuse
    if (tid < 256)                                 // 4 consecutive rows are contiguous: 4 KB
      xs4[tid] = ((const float4*)x)[ (int64_t)(b * T_ + t0c + t4) * 64 + tid ];
    __syncthreads();
    #pragma unroll
    for (int rr = 0; rr < 4; ++rr){
      const float4* xr = &xs4[rr * 64 + (ks >> 2)];
      float ax = 0.f, ay = 0.f, az = 0.f, aw = 0.f;
      #pragma unroll
      for (int q = 0; q < 8; ++q){
        float4 hv = xr[q];                         // broadcast read
        FMA4(hv.x, w4[4*q+0], ax, ay, az, aw);
        FMA4(hv.y, w4[4*q+1], ax, ay, az, aw);
        FMA4(hv.z, w4[4*q+2], ax, ay, az, aw);
        FMA4(hv.w, w4[4*q+3], ax, ay, az, aw);
      }
      *(float4*)&pb[wv][rr][4*lane] = make_float4(ax, ay, az, aw);
    }
    __syncthreads();
    if (tid < 256){
      float z0 = bias, z1 = bias, z2 = bias, z3 = bias;
      #pragma unroll
      for (int w = 0; w < 8; ++w){
        z0 += pb[w][0][tid]; z1 += pb[w][1][tid];
        z2 += pb[w][2][tid]; z3 += pb[w][3][tid];
      }
      *(float4*)&xp[ ((int64_t)b * H_ + tid) * Tc + t4 ] = make_float4(z0, z1, z2, z3);
    }
  }
}

// ---------- phase 2: 128 independent chains; k-split-8 matvec + LDS reduce + gates ----------

__global__ __launch_bounds__(512, 2) void rec_k(
    const float* __restrict__ xp, const float* __restrict__ w_h,
    float* __restrict__ out, int Tc, int init)
{
  const int tid  = threadIdx.x;
  const int wv   = tid >> 6;
  const int lane = tid & 63;
  const int ks   = wv * 32;
  const int b    = blockIdx.x;

  float4 w4[32];
  #pragma unroll
  for (int kk = 0; kk < 32; ++kk)
    w4[kk] = *(const float4*)&w_h[(ks + kk) * H_ + 4 * lane];

  __shared__ float hb[2][H_];                      // double-buffered h (fp32)
  __shared__ float pbuf[8][H_];                    // per-wave partials

  float c = 0.f, hn = 0.f;
  const float* xpr = nullptr;
  float4 xq = make_float4(0,0,0,0), xq_next = make_float4(0,0,0,0);
  if (tid < 256){
    float h0 = init ? 0.f : out[(int64_t)b * H_ + tid];
    hb[0][tid] = h0;
    hn = h0;
    c  = init ? 0.f : out[(int64_t)B_ * H_ + (int64_t)b * H_ + tid];
    xpr = xp + ((int64_t)b * H_ + tid) * Tc;
    xq_next = *(const float4*)xpr;                 // prefetch t=0..3
  }
  __syncthreads();
  int p = 0;
  for (int t = 0; t < Tc; t += 4){
    if (tid < 256){
      xq = xq_next;
      if (t + 4 < Tc) xq_next = *(const float4*)(xpr + t + 4);
    }
    #pragma unroll
    for (int tt = 0; tt < 4; ++tt){
      const float4* hr = (const float4*)&hb[p][ks];
      float ax = 0.f, ay = 0.f, az = 0.f, aw = 0.f;
      #pragma unroll
      for (int q = 0; q < 8; ++q){
        float4 hv = hr[q];                         // broadcast read of k-slice
        FMA4(hv.x, w4[4*q+0], ax, ay, az, aw);
        FMA4(hv.y, w4[4*q+1], ax, ay, az, aw);
        FMA4(hv.z, w4[4*q+2], ax, ay, az, aw);
        FMA4(hv.w, w4[4*q+3], ax, ay, az, aw);
      }
      *(float4*)&pbuf[wv][4*lane] = make_float4(ax, ay, az, aw);
      __syncthreads();
      if (tid < 256){
        float z = ((pbuf[0][tid] + pbuf[1][tid]) + (pbuf[2][tid] + pbuf[3][tid]))
                + ((pbuf[4][tid] + pbuf[5][tid]) + (pbuf[6][tid] + pbuf[7][tid]));
        z += (tt == 0) ? xq.x : (tt == 1) ? xq.y : (tt == 2) ? xq.z : xq.w;
        float s, g; gates_sg(z, s, g);
        c  = s * (c + g);
        hn = s * tanh_stable(c);
        hb[p ^ 1][tid] = hn;
      }
      __syncthreads();
      p ^= 1;
    }
  }
  if (tid < 256){
    out[(int64_t)b * H_ + tid] = hn;                       // h_T
    out[(int64_t)B_ * H_ + (int64_t)b * H_ + tid] = c;     // c_T
  }
}

// ---------- insurance fallback: fused, no workspace (rarely/never used) ----------

__global__ __launch_bounds__(512, 2) void lstm_fused_k(
    const float* __restrict__ x, const float* __restrict__ w_x,
    const float* __restrict__ b_x, const float* __restrict__ w_h,
    const float* __restrict__ b_h, float* __restrict__ out)
{
  const int tid  = threadIdx.x;
  const int wv   = tid >> 6;
  const int lane = tid & 63;
  const int ks   = wv * 32;
  const int b    = blockIdx.x;

  float4 wh4[32], wx4[32];                         // may spill; insurance path only
  #pragma unroll
  for (int kk = 0; kk < 32; ++kk){
    wh4[kk] = *(const float4*)&w_h[(ks + kk) * H_ + 4 * lane];
    wx4[kk] = *(const float4*)&w_x[(ks + kk) * H_ + 4 * lane];
  }
  float bias = 0.0f;
  if (tid < 256) bias = b_x[tid] + b_h[tid];

  __shared__ float hb[2][H_];
  __shared__ float4 xs4[2][64];
  const float* xrow = x + (int64_t)b * T_ * I_;
  if (tid < 256) hb[0][tid] = 0.f;
  if (tid < 64)  xs4[0][tid] = ((const float4*)xrow)[tid];
  __syncthreads();
  float c = 0.f, hn = 0.f;
  int p = 0;
  for (int t = 0; t < T_; ++t){
    const float4* hr = (const float4*)&hb[p][ks];
    const float4* xr = &xs4[p][ks >> 2];
    float ax = 0.f, ay = 0.f, az = 0.f, aw = 0.f;
    #pragma unroll
    for (int q = 0; q < 8; ++q){
      float4 hv = hr[q];
      FMA4(hv.x, wh4[4*q+0], ax, ay, az, aw);
      FMA4(hv.y, wh4[4*q+1], ax, ay, az, aw);
      FMA4(hv.z, wh4[4*q+2], ax, ay, az, aw);
      FMA4(hv.w, wh4[4*q+3], ax, ay, az, aw);
    }
    #pragma unroll
    for (int q = 0; q < 8; ++q){
      float4 xv = xr[q];
      FMA4(xv.x, wx4[4*q+0], ax, ay, az, aw);
      FMA4(xv.y, wx4[4*q+1], ax, ay, az, aw);
      FMA4(xv.z, wx4[4*q+2], ax, ay, az, aw);
      FMA4(xv.w, wx4[4*q+3], ax, ay, az, aw);
    }
    __shared__ float pbuf[8][H_];
    *(float4*)&pbuf[wv][4*lane] = make_float4(ax, ay, az, aw);
    __syncthreads();
    if (tid < 256){
      float z = bias
              + ((pbuf[0][tid] + pbuf[1][tid]) + (pbuf[2][tid] + pbuf[3][tid]))
              + ((pbuf[4][tid] + pbuf[5][tid]) + (pbuf[6][tid] + pbuf[7][tid]));
      float s, g; gates_sg(z, s, g);
      c  = s * (c + g);
      hn = s * tanh_stable(c);
      hb[p ^ 1][tid] = hn;
    } else if (tid < 320 && t + 1 < T_){
      xs4[p ^ 1][tid - 256] = ((const float4*)(xrow + (int64_t)(t + 1) * I_))[tid - 256];
    }
    __syncthreads();
    p ^= 1;
  }
  if (tid < 256){
    out[(int64_t)b * H_ + tid] = hn;
    out[(int64_t)B_ * H_ + (int64_t)b * H_ + tid] = c;
  }
}

// ---------- launch ----------

extern "C" void kernel_launch(void* const* d_in, const int* in_sizes, int n_in,
                              void* d_out, int out_size, void* d_ws, size_t ws_size,
                              hipStream_t stream)
{
  const float* x   = (const float*)d_in[0];
  const float* w_x = (const float*)d_in[1];
  const float* b_x = (const float*)d_in[2];
  const float* w_h = (const float*)d_in[3];
  const float* b_h = (const float*)d_in[4];
  float* out = (float*)d_out;

  const size_t per_t = (size_t)B_ * H_ * sizeof(float);   // bytes of xp per timestep
  int Tc_max = (int)((ws_size / per_t) & ~(size_t)3);
  if (Tc_max >= 4){
    if (Tc_max > T_) Tc_max = T_;
    int done = 0, first = 1;
    while (done < T_){
      int Tc = (T_ - done < Tc_max) ? (T_ - done) : Tc_max;
      xproj_k<<<256, 512, 0, stream>>>(x, w_x, b_x, b_h, (float*)d_ws, done, Tc);
      rec_k<<<128, 512, 0, stream>>>((const float*)d_ws, w_h, out, Tc, first);
      done += Tc; first = 0;
    }
  } else {
    lstm_fused_k<<<128, 512, 0, stream>>>(x, w_x, b_x, w_h, b_h, out);
  }
}

// Round 3
// 2211.047 us; speedup vs baseline: 1.0167x; 1.0167x over previous
//
#include <hip/hip_runtime.h>
#include <stdint.h>

#define B_ 128
#define T_ 2048
#define I_ 256
#define H_ 256

// ---------- gate helpers (overflow-safe, fp32) ----------

__device__ __forceinline__ void gates_sg(float z, float& s, float& g){
  float az = fabsf(z);
  float a  = __expf(-az);                          // in (0,1]
  float r1 = __builtin_amdgcn_rcpf(1.0f + a);
  s = (z >= 0.0f) ? r1 : a * r1;                   // sigmoid(z)
  float a2 = a * a;
  float gm = (1.0f - a2) * __builtin_amdgcn_rcpf(1.0f + a2);
  g = (z >= 0.0f) ? gm : -gm;                      // tanh(z)
}
__device__ __forceinline__ float tanh_stable(float c){
  float ac = fabsf(c);
  float u  = __expf(-2.0f * ac);                   // underflows to 0, never Inf
  float tm = (1.0f - u) * __builtin_amdgcn_rcpf(1.0f + u);
  return (c >= 0.0f) ? tm : -tm;
}

#define FMA4(hs, wv, ax, ay, az, aw)            \
  ax = fmaf(hs, wv.x, ax); ay = fmaf(hs, wv.y, ay); \
  az = fmaf(hs, wv.z, az); aw = fmaf(hs, wv.w, aw);

// ---------- phase 1: xp[b, j, t] = x[b,t,:] @ w_x[:,j] + b_x[j] + b_h[j]  (fp32, [B,H,Tc]) ----------
// 512 threads = 8 waves; wave w owns k-slice [32w,32w+32); lane owns cols 4*lane..4*lane+3.
// Blocked bid mapping: each WG owns a CONTIGUOUS t-range (one WG fills each xp cache line;
// x reads stream contiguously). x-tile is register-prefetched one iteration ahead.

__global__ __launch_bounds__(512, 2) void xproj_k(
    const float* __restrict__ x, const float* __restrict__ w_x,
    const float* __restrict__ b_x, const float* __restrict__ b_h,
    float* __restrict__ xp, int t0c, int Tc)
{
  const int tid  = threadIdx.x;
  const int wv   = tid >> 6;
  const int lane = tid & 63;
  const int ks   = wv * 32;

  float4 w4[32];                                   // col-slice of w_x (AGPR-backed is fine)
  #pragma unroll
  for (int kk = 0; kk < 32; ++kk)
    w4[kk] = *(const float4*)&w_x[(ks + kk) * H_ + 4 * lane];

  float bias = 0.0f;
  if (tid < 256) bias = b_x[tid] + b_h[tid];

  __shared__ float4 xs4[256];                      // 4 rows x 256 floats (4 KB)
  __shared__ float  pb[8][4][256];                 // [wave][row][col] (32 KB)

  const int rows_per_b = Tc >> 2;                  // 4-row blocks per batch row
  const int nblk  = (B_ * Tc) >> 2;
  const int iters = (nblk + gridDim.x - 1) / gridDim.x;
  const int bid0  = blockIdx.x * iters;            // contiguous range [bid0, bid0+iters)

  float4 r = make_float4(0,0,0,0);                 // prefetch register
  if (tid < 256 && bid0 < nblk){
    const int b  = bid0 / rows_per_b;
    const int t4 = (bid0 - b * rows_per_b) << 2;
    r = ((const float4*)x)[ (int64_t)(b * T_ + t0c + t4) * 64 + tid ];
  }

  for (int i = 0; i < iters; ++i){
    const int bid = bid0 + i;
    const bool valid = bid < nblk;
    if (tid < 256 && valid) xs4[tid] = r;          // stage current tile
    __syncthreads();                               // tile visible to all waves
    if (tid < 256 && bid + 1 < nblk){              // prefetch next tile (latency hidden by matvec)
      const int bn = bid + 1;
      const int b  = bn / rows_per_b;
      const int t4 = (bn - b * rows_per_b) << 2;
      r = ((const float4*)x)[ (int64_t)(b * T_ + t0c + t4) * 64 + tid ];
    }
    if (valid){
      #pragma unroll
      for (int rr = 0; rr < 4; ++rr){
        const float4* xr = &xs4[rr * 64 + (ks >> 2)];
        float ax = 0.f, ay = 0.f, az = 0.f, aw = 0.f;
        #pragma unroll
        for (int q = 0; q < 8; ++q){
          float4 hv = xr[q];                       // broadcast read
          FMA4(hv.x, w4[4*q+0], ax, ay, az, aw);
          FMA4(hv.y, w4[4*q+1], ax, ay, az, aw);
          FMA4(hv.z, w4[4*q+2], ax, ay, az, aw);
          FMA4(hv.w, w4[4*q+3], ax, ay, az, aw);
        }
        *(float4*)&pb[wv][rr][4*lane] = make_float4(ax, ay, az, aw);
      }
    }
    __syncthreads();                               // partials ready; xs4 consumed
    if (valid && tid < 256){
      const int b  = bid / rows_per_b;
      const int t4 = (bid - b * rows_per_b) << 2;
      float z0 = bias, z1 = bias, z2 = bias, z3 = bias;
      #pragma unroll
      for (int w = 0; w < 8; ++w){
        z0 += pb[w][0][tid]; z1 += pb[w][1][tid];
        z2 += pb[w][2][tid]; z3 += pb[w][3][tid];
      }
      *(float4*)&xp[ ((int64_t)b * H_ + tid) * Tc + t4 ] = make_float4(z0, z1, z2, z3);
    }
  }
}

// ---------- phase 2: 128 independent chains; ONE barrier per step ----------
// Wave w's k-slice == its gate col-slice == [32w, 32w+32).  After the partial
// barrier, wave w reduces+gates only its own 32 cols (lanes 0-31), keeps c
// in-lane, writes its h-slice into its PRIVATE hb region, and re-reads it
// broadcast with no barrier (same-wave LDS ops are in-order).

__global__ __launch_bounds__(512, 2) void rec_k(
    const float* __restrict__ xp, const float* __restrict__ w_h,
    float* __restrict__ out, int Tc, int init)
{
  const int tid  = threadIdx.x;
  const int wv   = tid >> 6;
  const int lane = tid & 63;
  const int ks   = wv * 32;
  const int b    = blockIdx.x;

  float4 w4[32];                                   // W[ks+kk][4*lane .. 4*lane+4)
  #pragma unroll
  for (int kk = 0; kk < 32; ++kk)
    w4[kk] = *(const float4*)&w_h[(ks + kk) * H_ + 4 * lane];

  __shared__ float hb[H_];                         // wave-private slices
  __shared__ float pbuf[2][8][H_];                 // double-buffered partials (16 KB)

  const int  col   = ks + (lane & 31);
  const bool owner = (lane < 32);

  float c = 0.f, hcur = 0.f;
  const float* xpr = xp + ((int64_t)b * H_ + col) * Tc;
  float xarr[4] = {0,0,0,0};
  float4 xq_next = make_float4(0,0,0,0);
  if (owner){
    hcur = init ? 0.f : out[(int64_t)b * H_ + col];
    c    = init ? 0.f : out[(int64_t)B_ * H_ + (int64_t)b * H_ + col];
    hb[col] = hcur;                                // own slice; same-wave readers below
    xq_next = *(const float4*)xpr;                 // prefetch t=0..3
  }
  __syncthreads();
  int pp = 0;
  for (int t = 0; t < Tc; t += 4){
    if (owner){
      xarr[0] = xq_next.x; xarr[1] = xq_next.y;
      xarr[2] = xq_next.z; xarr[3] = xq_next.w;
      if (t + 4 < Tc) xq_next = *(const float4*)(xpr + t + 4);   // 4-step lookahead
    }
    #pragma unroll
    for (int tt = 0; tt < 4; ++tt){
      // --- phase A: k-slice matvec (all 64 lanes) ---
      const float4* hr = (const float4*)&hb[ks];   // own slice, broadcast reads
      float ax = 0.f, ay = 0.f, az = 0.f, aw = 0.f;
      #pragma unroll
      for (int q = 0; q < 8; ++q){
        float4 hv = hr[q];
        FMA4(hv.x, w4[4*q+0], ax, ay, az, aw);
        FMA4(hv.y, w4[4*q+1], ax, ay, az, aw);
        FMA4(hv.z, w4[4*q+2], ax, ay, az, aw);
        FMA4(hv.w, w4[4*q+3], ax, ay, az, aw);
      }
      *(float4*)&pbuf[pp][wv][4*lane] = make_float4(ax, ay, az, aw);
      __syncthreads();                             // the ONLY barrier per step
      // --- phase B: reduce + gates for own 32 cols (lanes 0-31) ---
      if (owner){
        float z = xarr[tt];
        float p0 = pbuf[pp][0][col], p1 = pbuf[pp][1][col];
        float p2 = pbuf[pp][2][col], p3 = pbuf[pp][3][col];
        float p4 = pbuf[pp][4][col], p5 = pbuf[pp][5][col];
        float p6 = pbuf[pp][6][col], p7 = pbuf[pp][7][col];
        z += ((p0 + p1) + (p2 + p3)) + ((p4 + p5) + (p6 + p7));
        float s, g; gates_sg(z, s, g);
        c    = s * (c + g);
        hcur = s * tanh_stable(c);
        hb[col] = hcur;                            // own slice; next phase A (same wave) reads it
      }
      pp ^= 1;
    }
  }
  if (owner){
    out[(int64_t)b * H_ + col] = hcur;                         // h_T
    out[(int64_t)B_ * H_ + (int64_t)b * H_ + col] = c;         // c_T
  }
}

// ---------- insurance fallback: fused, no workspace (not expected to run) ----------

__global__ __launch_bounds__(512, 2) void lstm_fused_k(
    const float* __restrict__ x, const float* __restrict__ w_x,
    const float* __restrict__ b_x, const float* __restrict__ w_h,
    const float* __restrict__ b_h, float* __restrict__ out)
{
  const int tid  = threadIdx.x;
  const int wv   = tid >> 6;
  const int lane = tid & 63;
  const int ks   = wv * 32;
  const int b    = blockIdx.x;

  float4 wh4[32], wx4[32];
  #pragma unroll
  for (int kk = 0; kk < 32; ++kk){
    wh4[kk] = *(const float4*)&w_h[(ks + kk) * H_ + 4 * lane];
    wx4[kk] = *(const float4*)&w_x[(ks + kk) * H_ + 4 * lane];
  }
  float bias = 0.0f;
  if (tid < 256) bias = b_x[tid] + b_h[tid];

  __shared__ float hb[2][H_];
  __shared__ float4 xs4[2][64];
  __shared__ float pbuf[8][H_];
  const float* xrow = x + (int64_t)b * T_ * I_;
  if (tid < 256) hb[0][tid] = 0.f;
  if (tid < 64)  xs4[0][tid] = ((const float4*)xrow)[tid];
  __syncthreads();
  float c = 0.f, hn = 0.f;
  int p = 0;
  for (int t = 0; t < T_; ++t){
    const float4* hr = (const float4*)&hb[p][ks];
    const float4* xr = &xs4[p][ks >> 2];
    float ax = 0.f, ay = 0.f, az = 0.f, aw = 0.f;
    #pragma unroll
    for (int q = 0; q < 8; ++q){
      float4 hv = hr[q];
      FMA4(hv.x, wh4[4*q+0], ax, ay, az, aw);
      FMA4(hv.y, wh4[4*q+1], ax, ay, az, aw);
      FMA4(hv.z, wh4[4*q+2], ax, ay, az, aw);
      FMA4(hv.w, wh4[4*q+3], ax, ay, az, aw);
    }
    #pragma unroll
    for (int q = 0; q < 8; ++q){
      float4 xv = xr[q];
      FMA4(xv.x, wx4[4*q+0], ax, ay, az, aw);
      FMA4(xv.y, wx4[4*q+1], ax, ay, az, aw);
      FMA4(xv.z, wx4[4*q+2], ax, ay, az, aw);
      FMA4(xv.w, wx4[4*q+3], ax, ay, az, aw);
    }
    *(float4*)&pbuf[wv][4*lane] = make_float4(ax, ay, az, aw);
    __syncthreads();
    if (tid < 256){
      float z = bias
              + ((pbuf[0][tid] + pbuf[1][tid]) + (pbuf[2][tid] + pbuf[3][tid]))
              + ((pbuf[4][tid] + pbuf[5][tid]) + (pbuf[6][tid] + pbuf[7][tid]));
      float s, g; gates_sg(z, s, g);
      c  = s * (c + g);
      hn = s * tanh_stable(c);
      hb[p ^ 1][tid] = hn;
    } else if (tid < 320 && t + 1 < T_){
      xs4[p ^ 1][tid - 256] = ((const float4*)(xrow + (int64_t)(t + 1) * I_))[tid - 256];
    }
    __syncthreads();
    p ^= 1;
  }
  if (tid < 256){
    out[(int64_t)b * H_ + tid] = hn;
    out[(int64_t)B_ * H_ + (int64_t)b * H_ + tid] = c;
  }
}

// ---------- launch ----------

extern "C" void kernel_launch(void* const* d_in, const int* in_sizes, int n_in,
                              void* d_out, int out_size, void* d_ws, size_t ws_size,
                              hipStream_t stream)
{
  const float* x   = (const float*)d_in[0];
  const float* w_x = (const float*)d_in[1];
  const float* b_x = (const float*)d_in[2];
  const float* w_h = (const float*)d_in[3];
  const float* b_h = (const float*)d_in[4];
  float* out = (float*)d_out;

  const size_t per_t = (size_t)B_ * H_ * sizeof(float);   // bytes of xp per timestep
  int Tc_max = (int)((ws_size / per_t) & ~(size_t)3);
  if (Tc_max >= 4){
    if (Tc_max > T_) Tc_max = T_;
    int done = 0, first = 1;
    while (done < T_){
      int Tc = (T_ - done < Tc_max) ? (T_ - done) : Tc_max;
      xproj_k<<<256, 512, 0, stream>>>(x, w_x, b_x, b_h, (float*)d_ws, done, Tc);
      rec_k<<<128, 512, 0, stream>>>((const float*)d_ws, w_h, out, Tc, first);
      done += Tc; first = 0;
    }
  } else {
    lstm_fused_k<<<128, 512, 0, stream>>>(x, w_x, b_x, w_h, b_h, out);
  }
}

// Round 4
// 2164.259 us; speedup vs baseline: 1.0387x; 1.0216x over previous
//
#include <hip/hip_runtime.h>
#include <stdint.h>

#define B_ 128
#define T_ 2048
#define I_ 256
#define H_ 256

// ---------- gate helpers (overflow-safe, fp32) ----------

__device__ __forceinline__ void gates_sg(float z, float& s, float& g){
  float az = fabsf(z);
  float a  = __expf(-az);                          // in (0,1]
  float r1 = __builtin_amdgcn_rcpf(1.0f + a);
  s = (z >= 0.0f) ? r1 : a * r1;                   // sigmoid(z)
  float a2 = a * a;
  float gm = (1.0f - a2) * __builtin_amdgcn_rcpf(1.0f + a2);
  g = (z >= 0.0f) ? gm : -gm;                      // tanh(z)
}
__device__ __forceinline__ float tanh_stable(float c){
  float ac = fabsf(c);
  float u  = __expf(-2.0f * ac);                   // underflows to 0, never Inf
  float tm = (1.0f - u) * __builtin_amdgcn_rcpf(1.0f + u);
  return (c >= 0.0f) ? tm : -tm;
}

__device__ __forceinline__ float bcast_lane(float v, int srclane){
  return __builtin_bit_cast(float,
      __builtin_amdgcn_readlane(__builtin_bit_cast(int, v), srclane));
}

#define FMA4(hs, wv, ax, ay, az, aw)            \
  ax = fmaf(hs, wv.x, ax); ay = fmaf(hs, wv.y, ay); \
  az = fmaf(hs, wv.z, az); aw = fmaf(hs, wv.w, aw);

// ---------- phase 1: xp[b, j, t] = x[b,t,:] @ w_x[:,j] + b_x[j] + b_h[j]  (fp32, [B,H,Tc]) ----------
// 512 threads = 8 waves; wave w owns k-slice [32w,32w+32); lane owns cols 4*lane..4*lane+3.
// Grid 512 -> 2 WGs/CU (4 waves/SIMD): partner WG's FMAs hide barrier/LDS stalls.

__global__ __launch_bounds__(512, 2) void xproj_k(
    const float* __restrict__ x, const float* __restrict__ w_x,
    const float* __restrict__ b_x, const float* __restrict__ b_h,
    float* __restrict__ xp, int t0c, int Tc)
{
  const int tid  = threadIdx.x;
  const int wv   = tid >> 6;
  const int lane = tid & 63;
  const int ks   = wv * 32;

  float4 w4[32];                                   // col-slice of w_x
  #pragma unroll
  for (int kk = 0; kk < 32; ++kk)
    w4[kk] = *(const float4*)&w_x[(ks + kk) * H_ + 4 * lane];

  float bias = 0.0f;
  if (tid < 256) bias = b_x[tid] + b_h[tid];

  __shared__ float4 xs4[256];                      // 4 rows x 256 floats (4 KB)
  __shared__ float  pb[8][4][256];                 // [wave][row][col] (32 KB)

  const int rows_per_b = Tc >> 2;                  // 4-row blocks per batch row
  const int nblk  = (B_ * Tc) >> 2;
  const int iters = (nblk + gridDim.x - 1) / gridDim.x;
  const int bid0  = blockIdx.x * iters;            // contiguous range [bid0, bid0+iters)

  float4 r = make_float4(0,0,0,0);                 // prefetch register
  if (tid < 256 && bid0 < nblk){
    const int b  = bid0 / rows_per_b;
    const int t4 = (bid0 - b * rows_per_b) << 2;
    r = ((const float4*)x)[ (int64_t)(b * T_ + t0c + t4) * 64 + tid ];
  }

  for (int i = 0; i < iters; ++i){
    const int bid = bid0 + i;
    const bool valid = bid < nblk;
    if (tid < 256 && valid) xs4[tid] = r;          // stage current tile
    __syncthreads();                               // tile visible to all waves
    if (tid < 256 && bid + 1 < nblk){              // prefetch next tile
      const int bn = bid + 1;
      const int b  = bn / rows_per_b;
      const int t4 = (bn - b * rows_per_b) << 2;
      r = ((const float4*)x)[ (int64_t)(b * T_ + t0c + t4) * 64 + tid ];
    }
    if (valid){
      #pragma unroll
      for (int rr = 0; rr < 4; ++rr){
        const float4* xr = &xs4[rr * 64 + (ks >> 2)];
        float ax = 0.f, ay = 0.f, az = 0.f, aw = 0.f;
        #pragma unroll
        for (int q = 0; q < 8; ++q){
          float4 hv = xr[q];                       // broadcast read
          FMA4(hv.x, w4[4*q+0], ax, ay, az, aw);
          FMA4(hv.y, w4[4*q+1], ax, ay, az, aw);
          FMA4(hv.z, w4[4*q+2], ax, ay, az, aw);
          FMA4(hv.w, w4[4*q+3], ax, ay, az, aw);
        }
        *(float4*)&pb[wv][rr][4*lane] = make_float4(ax, ay, az, aw);
      }
    }
    __syncthreads();                               // partials ready; xs4 consumed
    if (valid && tid < 256){
      const int b  = bid / rows_per_b;
      const int t4 = (bid - b * rows_per_b) << 2;
      float z0 = bias, z1 = bias, z2 = bias, z3 = bias;
      #pragma unroll
      for (int w = 0; w < 8; ++w){
        z0 += pb[w][0][tid]; z1 += pb[w][1][tid];
        z2 += pb[w][2][tid]; z3 += pb[w][3][tid];
      }
      *(float4*)&xp[ ((int64_t)b * H_ + tid) * Tc + t4 ] = make_float4(z0, z1, z2, z3);
    }
  }
}

// ---------- phase 2: 128 independent chains; one barrier per step ----------
// Wave w's k-slice == its gate col-slice == [32w, 32w+32).
// h NEVER touches LDS: wave w's h-slice lives in its own lanes 0-31 and is
// broadcast to all lanes via v_readlane -> SGPRs (FMA takes SGPR operand).
// Cross-wave partial reduce distributed over all 64 lanes (4 b32 reads each,
// 2-way bank alias = free) + one shfl_down(32).

__global__ __launch_bounds__(512, 2) void rec_k(
    const float* __restrict__ xp, const float* __restrict__ w_h,
    float* __restrict__ out, int Tc, int init)
{
  const int tid  = threadIdx.x;
  const int wv   = tid >> 6;
  const int lane = tid & 63;
  const int ks   = wv * 32;
  const int b    = blockIdx.x;

  float4 w4[32];                                   // W[ks+kk][4*lane .. 4*lane+4)
  #pragma unroll
  for (int kk = 0; kk < 32; ++kk)
    w4[kk] = *(const float4*)&w_h[(ks + kk) * H_ + 4 * lane];

  __shared__ float pbuf[2][8][H_];                 // double-buffered partials (16 KB)

  const int  c32   = lane & 31;
  const int  col   = ks + c32;
  const int  hset  = lane >> 5;                    // 0 -> slots 0-3, 1 -> slots 4-7
  const bool owner = (lane < 32);

  float c = 0.f, hcur = 0.f;
  const float* xpr = xp + ((int64_t)b * H_ + col) * Tc;
  float xarr[4] = {0,0,0,0};
  float4 xq_next = make_float4(0,0,0,0);
  if (owner){
    hcur = init ? 0.f : out[(int64_t)b * H_ + col];
    c    = init ? 0.f : out[(int64_t)B_ * H_ + (int64_t)b * H_ + col];
    xq_next = *(const float4*)xpr;                 // prefetch t=0..3
  }
  int pp = 0;
  for (int t = 0; t < Tc; t += 4){
    if (owner){
      xarr[0] = xq_next.x; xarr[1] = xq_next.y;
      xarr[2] = xq_next.z; xarr[3] = xq_next.w;
      if (t + 4 < Tc) xq_next = *(const float4*)(xpr + t + 4);   // 4-step lookahead
    }
    #pragma unroll
    for (int tt = 0; tt < 4; ++tt){
      // --- phase A: broadcast own h-slice via readlane, then k-slice matvec ---
      float ax = 0.f, ay = 0.f, az = 0.f, aw = 0.f;
      #pragma unroll
      for (int q = 0; q < 8; ++q){
        float h0 = bcast_lane(hcur, 4*q+0);
        float h1 = bcast_lane(hcur, 4*q+1);
        float h2 = bcast_lane(hcur, 4*q+2);
        float h3 = bcast_lane(hcur, 4*q+3);
        FMA4(h0, w4[4*q+0], ax, ay, az, aw);
        FMA4(h1, w4[4*q+1], ax, ay, az, aw);
        FMA4(h2, w4[4*q+2], ax, ay, az, aw);
        FMA4(h3, w4[4*q+3], ax, ay, az, aw);
      }
      *(float4*)&pbuf[pp][wv][4*lane] = make_float4(ax, ay, az, aw);
      __syncthreads();                             // the ONLY barrier per step
      // --- phase B: distributed 8-way reduce + gates ---
      float sum = pbuf[pp][4*hset+0][col] + pbuf[pp][4*hset+1][col]
                + pbuf[pp][4*hset+2][col] + pbuf[pp][4*hset+3][col];
      sum += __shfl_down(sum, 32, 64);             // lanes 0-31: full 8-slot total
      if (owner){
        float z = xarr[tt] + sum;
        float s, g; gates_sg(z, s, g);
        c    = s * (c + g);
        hcur = s * tanh_stable(c);                 // next phase A readlanes this
      }
      pp ^= 1;
    }
  }
  if (owner){
    out[(int64_t)b * H_ + col] = hcur;                         // h_T
    out[(int64_t)B_ * H_ + (int64_t)b * H_ + col] = c;         // c_T
  }
}

// ---------- insurance fallback: fused, no workspace (not expected to run) ----------

__global__ __launch_bounds__(512, 2) void lstm_fused_k(
    const float* __restrict__ x, const float* __restrict__ w_x,
    const float* __restrict__ b_x, const float* __restrict__ w_h,
    const float* __restrict__ b_h, float* __restrict__ out)
{
  const int tid  = threadIdx.x;
  const int wv   = tid >> 6;
  const int lane = tid & 63;
  const int ks   = wv * 32;
  const int b    = blockIdx.x;

  float4 wh4[32], wx4[32];
  #pragma unroll
  for (int kk = 0; kk < 32; ++kk){
    wh4[kk] = *(const float4*)&w_h[(ks + kk) * H_ + 4 * lane];
    wx4[kk] = *(const float4*)&w_x[(ks + kk) * H_ + 4 * lane];
  }
  float bias = 0.0f;
  if (tid < 256) bias = b_x[tid] + b_h[tid];

  __shared__ float hb[2][H_];
  __shared__ float4 xs4[2][64];
  __shared__ float pbuf[8][H_];
  const float* xrow = x + (int64_t)b * T_ * I_;
  if (tid < 256) hb[0][tid] = 0.f;
  if (tid < 64)  xs4[0][tid] = ((const float4*)xrow)[tid];
  __syncthreads();
  float c = 0.f, hn = 0.f;
  int p = 0;
  for (int t = 0; t < T_; ++t){
    const float4* hr = (const float4*)&hb[p][ks];
    const float4* xr = &xs4[p][ks >> 2];
    float ax = 0.f, ay = 0.f, az = 0.f, aw = 0.f;
    #pragma unroll
    for (int q = 0; q < 8; ++q){
      float4 hv = hr[q];
      FMA4(hv.x, wh4[4*q+0], ax, ay, az, aw);
      FMA4(hv.y, wh4[4*q+1], ax, ay, az, aw);
      FMA4(hv.z, wh4[4*q+2], ax, ay, az, aw);
      FMA4(hv.w, wh4[4*q+3], ax, ay, az, aw);
    }
    #pragma unroll
    for (int q = 0; q < 8; ++q){
      float4 xv = xr[q];
      FMA4(xv.x, wx4[4*q+0], ax, ay, az, aw);
      FMA4(xv.y, wx4[4*q+1], ax, ay, az, aw);
      FMA4(xv.z, wx4[4*q+2], ax, ay, az, aw);
      FMA4(xv.w, wx4[4*q+3], ax, ay, az, aw);
    }
    *(float4*)&pbuf[wv][4*lane] = make_float4(ax, ay, az, aw);
    __syncthreads();
    if (tid < 256){
      float z = bias
              + ((pbuf[0][tid] + pbuf[1][tid]) + (pbuf[2][tid] + pbuf[3][tid]))
              + ((pbuf[4][tid] + pbuf[5][tid]) + (pbuf[6][tid] + pbuf[7][tid]));
      float s, g; gates_sg(z, s, g);
      c  = s * (c + g);
      hn = s * tanh_stable(c);
      hb[p ^ 1][tid] = hn;
    } else if (tid < 320 && t + 1 < T_){
      xs4[p ^ 1][tid - 256] = ((const float4*)(xrow + (int64_t)(t + 1) * I_))[tid - 256];
    }
    __syncthreads();
    p ^= 1;
  }
  if (tid < 256){
    out[(int64_t)b * H_ + tid] = hn;
    out[(int64_t)B_ * H_ + (int64_t)b * H_ + tid] = c;
  }
}

// ---------- launch ----------

extern "C" void kernel_launch(void* const* d_in, const int* in_sizes, int n_in,
                              void* d_out, int out_size, void* d_ws, size_t ws_size,
                              hipStream_t stream)
{
  const float* x   = (const float*)d_in[0];
  const float* w_x = (const float*)d_in[1];
  const float* b_x = (const float*)d_in[2];
  const float* w_h = (const float*)d_in[3];
  const float* b_h = (const float*)d_in[4];
  float* out = (float*)d_out;

  const size_t per_t = (size_t)B_ * H_ * sizeof(float);   // bytes of xp per timestep
  int Tc_max = (int)((ws_size / per_t) & ~(size_t)3);
  if (Tc_max >= 4){
    if (Tc_max > T_) Tc_max = T_;
    int done = 0, first = 1;
    while (done < T_){
      int Tc = (T_ - done < Tc_max) ? (T_ - done) : Tc_max;
      xproj_k<<<512, 512, 0, stream>>>(x, w_x, b_x, b_h, (float*)d_ws, done, Tc);
      rec_k<<<128, 512, 0, stream>>>((const float*)d_ws, w_h, out, Tc, first);
      done += Tc; first = 0;
    }
  } else {
    lstm_fused_k<<<128, 512, 0, stream>>>(x, w_x, b_x, w_h, b_h, out);
  }
}